// Round 1
// baseline (601.784 us; speedup 1.0000x reference)
//
#include <hip/hip_runtime.h>
#include <cstdint>
#include <cstddef>

#define HW 14400
#define WIDTH 120
#define S_TOT 110

typedef unsigned short u16;
typedef __attribute__((ext_vector_type(8))) short bf16x8;
typedef __attribute__((ext_vector_type(4))) float f32x4;

__device__ __forceinline__ u16 f2bf(float x) {
  unsigned u = __float_as_uint(x);
  unsigned r = (u + 0x7fffu + ((u >> 16) & 1u)) >> 16;
  return (u16)r;
}
__device__ __forceinline__ float bf2f(u16 h) {
  return __uint_as_float((unsigned)h << 16);
}

__device__ __forceinline__ void async16(void* lds, const void* g) {
  __builtin_amdgcn_global_load_lds(
      (const __attribute__((address_space(1))) void*)g,
      (__attribute__((address_space(3))) void*)lds, 16, 0, 0);
}

// ---------------------------------------------------------------------------
// Pyramid pooling: in [nplanes][14400] -> out [nplanes][110]
// ---------------------------------------------------------------------------
__global__ __launch_bounds__(256) void pool_kernel(const float* __restrict__ in,
                                                   float* __restrict__ outp) {
  __shared__ float part[576];
  const float* plane = in + (size_t)blockIdx.x * HW;
  int t = threadIdx.x;
  for (int bb = t; bb < 576; bb += 256) {
    int by = bb / 24, bx = bb % 24;
    const float* p0 = plane + (by * 5) * WIDTH + bx * 5;
    float s = 0.f;
#pragma unroll
    for (int yy = 0; yy < 5; ++yy)
#pragma unroll
      for (int xx = 0; xx < 5; ++xx) s += p0[yy * WIDTH + xx];
    part[bb] = s;
  }
  __syncthreads();
  if (t < S_TOT) {
    float s = 0.f;
    if (t == 0) {
      for (int i = 0; i < 576; ++i) s += part[i];
      s *= (1.f / 14400.f);
    } else if (t < 10) {
      int idx = t - 1, i = idx / 3, j = idx % 3;
      for (int a = 0; a < 8; ++a)
        for (int c = 0; c < 8; ++c) s += part[(i * 8 + a) * 24 + (j * 8 + c)];
      s *= (1.f / 1600.f);
    } else if (t < 46) {
      int idx = t - 10, i = idx / 6, j = idx % 6;
      for (int a = 0; a < 4; ++a)
        for (int c = 0; c < 4; ++c) s += part[(i * 4 + a) * 24 + (j * 4 + c)];
      s *= (1.f / 400.f);
    } else {
      int idx = t - 46, i = idx / 8, j = idx % 8;
      for (int a = 0; a < 3; ++a)
        for (int c = 0; c < 3; ++c) s += part[(i * 3 + a) * 24 + (j * 3 + c)];
      s *= (1.f / 225.f);
    }
    outp[(size_t)blockIdx.x * S_TOT + t] = s;
  }
}

// ---------------------------------------------------------------------------
// Split fp32 weight -> bf16 hi/lo (elementwise)
// ---------------------------------------------------------------------------
__global__ __launch_bounds__(256) void convert_w(const float* __restrict__ in,
                                                 u16* __restrict__ hi,
                                                 u16* __restrict__ lo, int n) {
  int i = blockIdx.x * 256 + threadIdx.x;
  if (i < n) {
    float v = in[i];
    u16 h = f2bf(v);
    hi[i] = h;
    lo[i] = f2bf(v - bf2f(h));
  }
}

// ---------------------------------------------------------------------------
// X [b][CIN][14400] fp32 -> XT hi/lo [b][14400][CIN] bf16 (transpose + split)
// ---------------------------------------------------------------------------
template <int CIN>
__global__ __launch_bounds__(256) void convert_t(const float* __restrict__ X,
                                                 u16* __restrict__ xth,
                                                 u16* __restrict__ xtl) {
  __shared__ float ls[64][65];
  int b = blockIdx.z;
  int n0 = blockIdx.x * 64, k0 = blockIdx.y * 64;
  int t = threadIdx.x;
  int rt = t >> 4, c4 = (t & 15) * 4;
#pragma unroll
  for (int rr = 0; rr < 4; ++rr) {
    int kk = rr * 16 + rt;
    float4 v = *(const float4*)&X[((size_t)(b * CIN + k0 + kk)) * HW + n0 + c4];
    ls[kk][c4] = v.x; ls[kk][c4 + 1] = v.y; ls[kk][c4 + 2] = v.z; ls[kk][c4 + 3] = v.w;
  }
  __syncthreads();
#pragma unroll
  for (int rr = 0; rr < 4; ++rr) {
    int nn = rr * 16 + rt;
    float v0 = ls[c4 + 0][nn], v1 = ls[c4 + 1][nn], v2 = ls[c4 + 2][nn], v3 = ls[c4 + 3][nn];
    ushort4 oh, ol;
    oh.x = f2bf(v0); ol.x = f2bf(v0 - bf2f(oh.x));
    oh.y = f2bf(v1); ol.y = f2bf(v1 - bf2f(oh.y));
    oh.z = f2bf(v2); ol.z = f2bf(v2 - bf2f(oh.z));
    oh.w = f2bf(v3); ol.w = f2bf(v3 - bf2f(oh.w));
    size_t idx = ((size_t)(b * HW + n0 + nn)) * CIN + k0 + c4;
    *(ushort4*)&xth[idx] = oh;
    *(ushort4*)&xtl[idx] = ol;
  }
}

// ---------------------------------------------------------------------------
// Split-bf16 MFMA GEMM v2:  C[b][m][n] = epi( sum_k A[m][k]*B[b][n][k] )
//  - A fragments loaded DIRECTLY from global (weights are 512KB, L2-hot;
//    skips LDS staging + drain + bank conflicts).
//  - B double-buffered in LDS, fragment-major (lane-linear, conflict-free),
//    staged one k-step ahead via global_load_lds (attn-style prefetch).
//    A-loads are issued BEFORE stage(ks+1) so the compiler's vmcnt wait for
//    A leaves the younger stage ops in flight (vmcnt is in-order).
//  - One __syncthreads per k-step: drains stage(ks), protects buf reuse.
//  - Optional fused transposed split-bf16 store (Th/Tl, [b][n][M_TOT]) for
//    the kq GEMM, replacing the separate convert_t<256> dispatch.
// ---------------------------------------------------------------------------
template <int K, int M_TOT, bool BNRELU>
__global__ __launch_bounds__(256) void gemm_mfma(
    const u16* __restrict__ Ah, const u16* __restrict__ Al,
    const u16* __restrict__ Bh, const u16* __restrict__ Bl,
    float* __restrict__ C,
    const float* __restrict__ p0, const float* __restrict__ p1,
    const float* __restrict__ p2, const float* __restrict__ p3,
    const float* __restrict__ p4,
    u16* __restrict__ Th, u16* __restrict__ Tl) {
  constexpr int NSTEP = K / 32;
  // B double-buffer, fragment-major: [buf][half][nt][lane][8 u16] = 16 KB
  __shared__ alignas(16) u16 sB[2][2][4][64][8];
  __shared__ float sP0[256], sP1[256];

  int t = threadIdx.x, w = t >> 6, l = t & 63;
  int b = blockIdx.z;
  int n0 = blockIdx.x * 64;
  int m0 = blockIdx.y * 256;

  if (BNRELU) {
    int m = m0 + t;
    float iv = p1[m] * rsqrtf(p4[m] + 1e-5f);
    sP0[t] = iv;
    sP1[t] = (p0[m] - p3[m]) * iv + p2[m];
  } else {
    sP0[t] = p0[m0 + t];
  }

  int fr = l & 15, fkc = l >> 4;
  const size_t bOff = (size_t)b * HW;

  // stage one 32-k slice of B (hi+lo) into buf; wave w handles frags i=2w,2w+1
  auto stageB = [&](int ks, int buf) {
    int k0 = ks * 32;
#pragma unroll
    for (int c = 0; c < 2; ++c) {
      int i = w * 2 + c;
      int half = i >> 2, nt = i & 3;
      const u16* src = (half ? Bl : Bh) +
                       (bOff + n0 + nt * 16 + fr) * (size_t)K + k0 + fkc * 8;
      async16(&sB[buf][half][nt][l][0], src);
    }
  };

  f32x4 acc[4][4];
#pragma unroll
  for (int i = 0; i < 4; ++i)
#pragma unroll
    for (int j = 0; j < 4; ++j) acc[i][j] = (f32x4){0.f, 0.f, 0.f, 0.f};

  const u16* aRow_h = Ah + (size_t)(m0 + w * 64 + fr) * K + fkc * 8;
  const u16* aRow_l = Al + (size_t)(m0 + w * 64 + fr) * K + fkc * 8;

  stageB(0, 0);

  for (int ks = 0; ks < NSTEP; ++ks) {
    __syncthreads();  // drains stage(ks); all reads of buf^1 from ks-1 done
    // A fragments direct from global (issued first: oldest in vmcnt order)
    bf16x8 ah[4], al[4];
#pragma unroll
    for (int mt = 0; mt < 4; ++mt) {
      ah[mt] = *(const bf16x8*)(aRow_h + (size_t)mt * 16 * K + ks * 32);
      al[mt] = *(const bf16x8*)(aRow_l + (size_t)mt * 16 * K + ks * 32);
    }
    if (ks + 1 < NSTEP) stageB(ks + 1, (ks + 1) & 1);  // prefetch next slice
    bf16x8 bh[4], bl[4];
#pragma unroll
    for (int nt = 0; nt < 4; ++nt) {
      bh[nt] = *(const bf16x8*)&sB[ks & 1][0][nt][l][0];
      bl[nt] = *(const bf16x8*)&sB[ks & 1][1][nt][l][0];
    }
#pragma unroll
    for (int mt = 0; mt < 4; ++mt)
#pragma unroll
      for (int nt = 0; nt < 4; ++nt) {
        acc[mt][nt] = __builtin_amdgcn_mfma_f32_16x16x32_bf16(ah[mt], bh[nt], acc[mt][nt], 0, 0, 0);
        acc[mt][nt] = __builtin_amdgcn_mfma_f32_16x16x32_bf16(ah[mt], bl[nt], acc[mt][nt], 0, 0, 0);
        acc[mt][nt] = __builtin_amdgcn_mfma_f32_16x16x32_bf16(al[mt], bh[nt], acc[mt][nt], 0, 0, 0);
      }
  }

#pragma unroll
  for (int mt = 0; mt < 4; ++mt) {
    int lmBase = w * 64 + mt * 16 + (l >> 4) * 4;
#pragma unroll
    for (int nt = 0; nt < 4; ++nt) {
      int n = n0 + nt * 16 + fr;
      if (BNRELU) {
        float v0 = fmaxf(acc[mt][nt][0] * sP0[lmBase + 0] + sP1[lmBase + 0], 0.f);
        float v1 = fmaxf(acc[mt][nt][1] * sP0[lmBase + 1] + sP1[lmBase + 1], 0.f);
        float v2 = fmaxf(acc[mt][nt][2] * sP0[lmBase + 2] + sP1[lmBase + 2], 0.f);
        float v3 = fmaxf(acc[mt][nt][3] * sP0[lmBase + 3] + sP1[lmBase + 3], 0.f);
        C[((size_t)(b * M_TOT + m0 + lmBase + 0)) * HW + n] = v0;
        C[((size_t)(b * M_TOT + m0 + lmBase + 1)) * HW + n] = v1;
        C[((size_t)(b * M_TOT + m0 + lmBase + 2)) * HW + n] = v2;
        C[((size_t)(b * M_TOT + m0 + lmBase + 3)) * HW + n] = v3;
        if (Th) {
          ushort4 oh, ol;
          oh.x = f2bf(v0); ol.x = f2bf(v0 - bf2f(oh.x));
          oh.y = f2bf(v1); ol.y = f2bf(v1 - bf2f(oh.y));
          oh.z = f2bf(v2); ol.z = f2bf(v2 - bf2f(oh.z));
          oh.w = f2bf(v3); ol.w = f2bf(v3 - bf2f(oh.w));
          size_t o = (bOff + n) * (size_t)M_TOT + m0 + lmBase;
          *(ushort4*)&Th[o] = oh;
          *(ushort4*)&Tl[o] = ol;
        }
      } else {
#pragma unroll
        for (int r = 0; r < 4; ++r) {
          int lm = lmBase + r;
          C[((size_t)(b * M_TOT + m0 + lm)) * HW + n] = acc[mt][nt][r] + sP0[lm];
        }
      }
    }
  }
}

// ---------------------------------------------------------------------------
// valueT[b][cv][128] hi/lo = Wv[cv,:] . xp[b,:,s] + bv[cv]  (s>=110 -> 0)
// ---------------------------------------------------------------------------
__global__ __launch_bounds__(256) void value_kernel(
    const float* __restrict__ Wv, const float* __restrict__ xp,
    const float* __restrict__ bv, u16* __restrict__ vth,
    u16* __restrict__ vtl) {
  int b = blockIdx.x >> 7, s = blockIdx.x & 127;
  int t = threadIdx.x;
  size_t o = ((size_t)(b * 256 + t)) * 128 + s;
  if (s >= S_TOT) { vth[o] = 0; vtl[o] = 0; return; }
  __shared__ float xs[512];
  for (int i = t; i < 512; i += 256) xs[i] = xp[((size_t)b * 512 + i) * S_TOT + s];
  __syncthreads();
  float accv = 0.f;
  const float* wv = Wv + (size_t)t * 512;
  for (int k = 0; k < 512; k += 4) {
    float4 w4 = *(const float4*)&wv[k];
    accv += w4.x * xs[k] + w4.y * xs[k + 1] + w4.z * xs[k + 2] + w4.w * xs[k + 3];
  }
  accv += bv[t];
  u16 h = f2bf(accv);
  vth[o] = h;
  vtl[o] = f2bf(accv - bf2f(h));
}

// ---------------------------------------------------------------------------
// keypT[b][128][256] hi/lo from keyp [b][256][110] fp32 (s>=110 -> 0)
// ---------------------------------------------------------------------------
__global__ __launch_bounds__(256) void convert_key(const float* __restrict__ keyp,
                                                   u16* __restrict__ kth,
                                                   u16* __restrict__ ktl) {
  int b = blockIdx.x;
  int t = threadIdx.x;
  for (int i = t; i < 128 * 256; i += 256) {
    int s = i >> 8, c = i & 255;
    float v = (s < S_TOT) ? keyp[((size_t)(b * 256 + c)) * S_TOT + s] : 0.f;
    u16 h = f2bf(v);
    size_t o = ((size_t)(b * 128 + s)) * 256 + c;
    kth[o] = h;
    ktl[o] = f2bf(v - bf2f(h));
  }
}

// ---------------------------------------------------------------------------
// MFMA attention v2. Per block: 64 pixels, 4 waves. (unchanged)
// ---------------------------------------------------------------------------
__global__ __launch_bounds__(256) void attn_mfma(
    const u16* __restrict__ qh, const u16* __restrict__ ql,
    const u16* __restrict__ kh, const u16* __restrict__ kl,
    const u16* __restrict__ vh, const u16* __restrict__ vl,
    u16* __restrict__ aggh, u16* __restrict__ aggl) {
  __shared__ alignas(16) u16 lds[17408];
  int b = blockIdx.y, pix0 = blockIdx.x * 64;
  int t = threadIdx.x, w = t >> 6, l = t & 63;
  int fr = l & 15, q = l >> 4;

  const u16* kbase_h = kh + (size_t)b * 128 * 256;
  const u16* kbase_l = kl + (size_t)b * 128 * 256;

  f32x4 acc[8];
#pragma unroll
  for (int st = 0; st < 8; ++st) acc[st] = (f32x4){0.f, 0.f, 0.f, 0.f};

  const u16* qbh = qh + ((size_t)(b * HW + pix0 + w * 16 + fr)) * 256 + q * 8;
  const u16* qbl = ql + ((size_t)(b * HW + pix0 + w * 16 + fr)) * 256 + q * 8;

  auto stageK = [&](int ks, int buf) {
    int c0 = ks * 32;
#pragma unroll
    for (int j = 0; j < 4; ++j) {
      int i = t + j * 256;
      int half = i >> 9;
      int idx = i & 511;
      int st = idx >> 6, ll = idx & 63;
      const u16* src = (half ? kbase_l : kbase_h) +
                       (st * 16 + (ll & 15)) * 256 + c0 + (ll >> 4) * 8;
      async16(&lds[buf * 8192 + half * 4096 + idx * 8], src);
    }
  };

  stageK(0, 0);
  for (int ks = 0; ks < 8; ++ks) {
    __syncthreads();
    if (ks < 7) stageK(ks + 1, (ks + 1) & 1);
    bf16x8 ah = *(const bf16x8*)(qbh + ks * 32);
    bf16x8 al = *(const bf16x8*)(qbl + ks * 32);
    const u16* kb = &lds[(ks & 1) * 8192 + l * 8];
#pragma unroll
    for (int st = 0; st < 8; ++st) {
      bf16x8 bh = *(const bf16x8*)(kb + st * 512);
      bf16x8 bl = *(const bf16x8*)(kb + 4096 + st * 512);
      acc[st] = __builtin_amdgcn_mfma_f32_16x16x32_bf16(ah, bh, acc[st], 0, 0, 0);
      acc[st] = __builtin_amdgcn_mfma_f32_16x16x32_bf16(ah, bl, acc[st], 0, 0, 0);
      acc[st] = __builtin_amdgcn_mfma_f32_16x16x32_bf16(al, bh, acc[st], 0, 0, 0);
    }
  }

#pragma unroll
  for (int st = 0; st < 8; ++st)
#pragma unroll
    for (int r = 0; r < 4; ++r) acc[st][r] *= 0.0625f;
  if (fr >= 14) {
#pragma unroll
    for (int r = 0; r < 4; ++r) acc[6][r] = -1e30f;
  }
#pragma unroll
  for (int r = 0; r < 4; ++r) acc[7][r] = -1e30f;

#pragma unroll
  for (int r = 0; r < 4; ++r) {
    float m = -1e30f;
#pragma unroll
    for (int st = 0; st < 8; ++st) m = fmaxf(m, acc[st][r]);
    m = fmaxf(m, __shfl_xor(m, 1));
    m = fmaxf(m, __shfl_xor(m, 2));
    m = fmaxf(m, __shfl_xor(m, 4));
    m = fmaxf(m, __shfl_xor(m, 8));
    float s = 0.f;
#pragma unroll
    for (int st = 0; st < 8; ++st) {
      float e = __expf(acc[st][r] - m);
      acc[st][r] = e;
      s += e;
    }
    s += __shfl_xor(s, 1);
    s += __shfl_xor(s, 2);
    s += __shfl_xor(s, 4);
    s += __shfl_xor(s, 8);
    float inv = 1.f / s;
#pragma unroll
    for (int st = 0; st < 8; ++st) acc[st][r] *= inv;
  }

  __syncthreads();

  int prow = w * 16 + q * 4;
#pragma unroll
  for (int st = 0; st < 8; ++st) {
    int s = st * 16 + fr;
#pragma unroll
    for (int r = 0; r < 4; ++r) {
      float v = acc[st][r];
      u16 h = f2bf(v);
      lds[(prow + r) * 136 + s] = h;
      lds[8704 + (prow + r) * 136 + s] = f2bf(v - bf2f(h));
    }
  }
  __syncthreads();

  f32x4 oacc[4][4];
#pragma unroll
  for (int nt = 0; nt < 4; ++nt)
#pragma unroll
    for (int pt = 0; pt < 4; ++pt) oacc[nt][pt] = (f32x4){0.f, 0.f, 0.f, 0.f};

  const u16* vbh = vh + ((size_t)(b * 256 + w * 64 + fr)) * 128 + q * 8;
  const u16* vbl = vl + ((size_t)(b * 256 + w * 64 + fr)) * 128 + q * 8;

#pragma unroll
  for (int kc = 0; kc < 4; ++kc) {
    bf16x8 ph[4], pl[4];
#pragma unroll
    for (int pt = 0; pt < 4; ++pt) {
      ph[pt] = *(const bf16x8*)&lds[(pt * 16 + fr) * 136 + kc * 32 + q * 8];
      pl[pt] = *(const bf16x8*)&lds[8704 + (pt * 16 + fr) * 136 + kc * 32 + q * 8];
    }
#pragma unroll
    for (int nt = 0; nt < 4; ++nt) {
      bf16x8 a_h = *(const bf16x8*)(vbh + (size_t)nt * 16 * 128 + kc * 32);
      bf16x8 a_l = *(const bf16x8*)(vbl + (size_t)nt * 16 * 128 + kc * 32);
#pragma unroll
      for (int pt = 0; pt < 4; ++pt) {
        oacc[nt][pt] = __builtin_amdgcn_mfma_f32_16x16x32_bf16(a_h, ph[pt], oacc[nt][pt], 0, 0, 0);
        oacc[nt][pt] = __builtin_amdgcn_mfma_f32_16x16x32_bf16(a_h, pl[pt], oacc[nt][pt], 0, 0, 0);
        oacc[nt][pt] = __builtin_amdgcn_mfma_f32_16x16x32_bf16(a_l, ph[pt], oacc[nt][pt], 0, 0, 0);
      }
    }
  }

#pragma unroll
  for (int nt = 0; nt < 4; ++nt) {
#pragma unroll
    for (int pt = 0; pt < 4; ++pt) {
      ushort4 oh, ol;
      float v0 = oacc[nt][pt][0], v1 = oacc[nt][pt][1];
      float v2 = oacc[nt][pt][2], v3 = oacc[nt][pt][3];
      oh.x = f2bf(v0); ol.x = f2bf(v0 - bf2f(oh.x));
      oh.y = f2bf(v1); ol.y = f2bf(v1 - bf2f(oh.y));
      oh.z = f2bf(v2); ol.z = f2bf(v2 - bf2f(oh.z));
      oh.w = f2bf(v3); ol.w = f2bf(v3 - bf2f(oh.w));
      size_t o = ((size_t)(b * HW + pix0 + pt * 16 + fr)) * 256 + (w * 4 + nt) * 16 + q * 4;
      *(ushort4*)&aggh[o] = oh;
      *(ushort4*)&aggl[o] = ol;
    }
  }
}

extern "C" void kernel_launch(void* const* d_in, const int* in_sizes, int n_in,
                              void* d_out, int out_size, void* d_ws, size_t ws_size,
                              hipStream_t stream) {
  (void)in_sizes; (void)n_in; (void)out_size;
  const float* x     = (const float*)d_in[0];
  const float* Wk    = (const float*)d_in[1];
  const float* bk    = (const float*)d_in[2];
  const float* gamma = (const float*)d_in[3];
  const float* beta  = (const float*)d_in[4];
  const float* mean  = (const float*)d_in[5];
  const float* var   = (const float*)d_in[6];
  const float* Wv    = (const float*)d_in[7];
  const float* bv    = (const float*)d_in[8];
  const float* Wo    = (const float*)d_in[9];
  const float* bo    = (const float*)d_in[10];
  float* out = (float*)d_out;

  char* p = (char*)d_ws;
  float* kq = (float*)p;      p += (size_t)14745600 * 4;   // 4*256*14400 fp32
  u16* xth = (u16*)p;         p += (size_t)29491200 * 2;   // 4*14400*512 bf16
  u16* xtl = (u16*)p;         p += (size_t)29491200 * 2;
  u16* wkh = (u16*)p;         p += 131072 * 2;
  u16* wkl = (u16*)p;         p += 131072 * 2;
  u16* woh = (u16*)p;         p += 131072 * 2;
  u16* wol = (u16*)p;         p += 131072 * 2;
  float* xp = (float*)p;      p += (size_t)4 * 512 * 110 * 4;
  float* keyp = (float*)p;    p += (size_t)4 * 256 * 110 * 4;
  u16* vth = (u16*)p;         p += (size_t)4 * 256 * 128 * 2;
  u16* vtl = (u16*)p;         p += (size_t)4 * 256 * 128 * 2;
  u16* kth = (u16*)p;         p += (size_t)4 * 128 * 256 * 2;
  u16* ktl = (u16*)p;         p += (size_t)4 * 128 * 256 * 2;
  // Fused kqT path needs its own buffers (cannot alias xth/xtl: gemm_kq reads
  // those as B while writing kqT). Fall back to convert_t if ws too small.
  u16* kqth_f = (u16*)p;      p += (size_t)14745600 * 2;   // 4*14400*256 bf16
  u16* kqtl_f = (u16*)p;      p += (size_t)14745600 * 2;
  bool fused = ((size_t)(p - (char*)d_ws) <= ws_size);

  // aliases: xth/xtl (59MB each) are dead after gemm_kq.
  // first half -> agg hi/lo; second half -> kqT hi/lo (fallback only)
  u16* aggh = xth;
  u16* aggl = xtl;
  u16* kqth = fused ? kqth_f : xth + (size_t)14745600;
  u16* kqtl = fused ? kqtl_f : xtl + (size_t)14745600;

  // weight splits
  convert_w<<<512, 256, 0, stream>>>(Wk, wkh, wkl, 256 * 512);
  convert_w<<<512, 256, 0, stream>>>(Wo, woh, wol, 512 * 256);
  // X -> transposed bf16 hi/lo
  convert_t<512><<<dim3(225, 8, 4), 256, 0, stream>>>(x, xth, xtl);
  // pyramid-pool x (pooling commutes with 1x1 conv for value)
  pool_kernel<<<dim3(4 * 512), dim3(256), 0, stream>>>(x, xp);
  // valueT = split(conv_v(pooled x) + bv), s-padded
  value_kernel<<<dim3(4 * 128), dim3(256), 0, stream>>>(Wv, xp, bv, vth, vtl);
  // kq = relu(BN(conv_k(x)))  [split-bf16 MFMA] (+ fused kqT split store)
  gemm_mfma<512, 256, true><<<dim3(225, 1, 4), 256, 0, stream>>>(
      wkh, wkl, xth, xtl, kq, bk, gamma, beta, mean, var,
      fused ? kqth : (u16*)nullptr, fused ? kqtl : (u16*)nullptr);
  // kqT (query in A-fragment layout) -- only if not fused into gemm epilogue
  if (!fused)
    convert_t<256><<<dim3(225, 4, 4), 256, 0, stream>>>(kq, kqth, kqtl);
  // key = ppm(kq) -> keypT split, s-padded
  pool_kernel<<<dim3(4 * 256), dim3(256), 0, stream>>>(kq, keyp);
  convert_key<<<dim3(4), dim3(256), 0, stream>>>(keyp, kth, ktl);
  // fused MFMA attention -> agg split bf16
  attn_mfma<<<dim3(225, 4), 256, 0, stream>>>(kqth, kqtl, kth, ktl, vth, vtl,
                                              aggh, aggl);
  // out = conv_out(agg) + bo  [split-bf16 MFMA]
  gemm_mfma<256, 512, false><<<dim3(225, 2, 4), 256, 0, stream>>>(
      woh, wol, aggh, aggl, out, bo, nullptr, nullptr, nullptr, nullptr,
      nullptr, nullptr);
}

// Round 2
// 578.871 us; speedup vs baseline: 1.0396x; 1.0396x over previous
//
#include <hip/hip_runtime.h>
#include <cstdint>
#include <cstddef>

#define HW 14400
#define WIDTH 120
#define S_TOT 110

typedef unsigned short u16;
typedef __attribute__((ext_vector_type(8))) short bf16x8;
typedef __attribute__((ext_vector_type(4))) float f32x4;

__device__ __forceinline__ u16 f2bf(float x) {
  unsigned u = __float_as_uint(x);
  unsigned r = (u + 0x7fffu + ((u >> 16) & 1u)) >> 16;
  return (u16)r;
}
__device__ __forceinline__ float bf2f(u16 h) {
  return __uint_as_float((unsigned)h << 16);
}

__device__ __forceinline__ void async16(void* lds, const void* g) {
  __builtin_amdgcn_global_load_lds(
      (const __attribute__((address_space(1))) void*)g,
      (__attribute__((address_space(3))) void*)lds, 16, 0, 0);
}

// ---------------------------------------------------------------------------
// Pyramid pooling: in [nplanes][14400] -> out [nplanes][110]
// ---------------------------------------------------------------------------
__global__ __launch_bounds__(256) void pool_kernel(const float* __restrict__ in,
                                                   float* __restrict__ outp) {
  __shared__ float part[576];
  const float* plane = in + (size_t)blockIdx.x * HW;
  int t = threadIdx.x;
  for (int bb = t; bb < 576; bb += 256) {
    int by = bb / 24, bx = bb % 24;
    const float* p0 = plane + (by * 5) * WIDTH + bx * 5;
    float s = 0.f;
#pragma unroll
    for (int yy = 0; yy < 5; ++yy)
#pragma unroll
      for (int xx = 0; xx < 5; ++xx) s += p0[yy * WIDTH + xx];
    part[bb] = s;
  }
  __syncthreads();
  if (t < S_TOT) {
    float s = 0.f;
    if (t == 0) {
      for (int i = 0; i < 576; ++i) s += part[i];
      s *= (1.f / 14400.f);
    } else if (t < 10) {
      int idx = t - 1, i = idx / 3, j = idx % 3;
      for (int a = 0; a < 8; ++a)
        for (int c = 0; c < 8; ++c) s += part[(i * 8 + a) * 24 + (j * 8 + c)];
      s *= (1.f / 1600.f);
    } else if (t < 46) {
      int idx = t - 10, i = idx / 6, j = idx % 6;
      for (int a = 0; a < 4; ++a)
        for (int c = 0; c < 4; ++c) s += part[(i * 4 + a) * 24 + (j * 4 + c)];
      s *= (1.f / 400.f);
    } else {
      int idx = t - 46, i = idx / 8, j = idx % 8;
      for (int a = 0; a < 3; ++a)
        for (int c = 0; c < 3; ++c) s += part[(i * 3 + a) * 24 + (j * 3 + c)];
      s *= (1.f / 225.f);
    }
    outp[(size_t)blockIdx.x * S_TOT + t] = s;
  }
}

// ---------------------------------------------------------------------------
// Split fp32 weight -> bf16 hi/lo (elementwise)
// ---------------------------------------------------------------------------
__global__ __launch_bounds__(256) void convert_w(const float* __restrict__ in,
                                                 u16* __restrict__ hi,
                                                 u16* __restrict__ lo, int n) {
  int i = blockIdx.x * 256 + threadIdx.x;
  if (i < n) {
    float v = in[i];
    u16 h = f2bf(v);
    hi[i] = h;
    lo[i] = f2bf(v - bf2f(h));
  }
}

// ---------------------------------------------------------------------------
// X [b][CIN][14400] fp32 -> XT hi/lo [b][14400][CIN] bf16 (transpose + split)
// ---------------------------------------------------------------------------
template <int CIN>
__global__ __launch_bounds__(256) void convert_t(const float* __restrict__ X,
                                                 u16* __restrict__ xth,
                                                 u16* __restrict__ xtl) {
  __shared__ float ls[64][65];
  int b = blockIdx.z;
  int n0 = blockIdx.x * 64, k0 = blockIdx.y * 64;
  int t = threadIdx.x;
  int rt = t >> 4, c4 = (t & 15) * 4;
#pragma unroll
  for (int rr = 0; rr < 4; ++rr) {
    int kk = rr * 16 + rt;
    float4 v = *(const float4*)&X[((size_t)(b * CIN + k0 + kk)) * HW + n0 + c4];
    ls[kk][c4] = v.x; ls[kk][c4 + 1] = v.y; ls[kk][c4 + 2] = v.z; ls[kk][c4 + 3] = v.w;
  }
  __syncthreads();
#pragma unroll
  for (int rr = 0; rr < 4; ++rr) {
    int nn = rr * 16 + rt;
    float v0 = ls[c4 + 0][nn], v1 = ls[c4 + 1][nn], v2 = ls[c4 + 2][nn], v3 = ls[c4 + 3][nn];
    ushort4 oh, ol;
    oh.x = f2bf(v0); ol.x = f2bf(v0 - bf2f(oh.x));
    oh.y = f2bf(v1); ol.y = f2bf(v1 - bf2f(oh.y));
    oh.z = f2bf(v2); ol.z = f2bf(v2 - bf2f(oh.z));
    oh.w = f2bf(v3); ol.w = f2bf(v3 - bf2f(oh.w));
    size_t idx = ((size_t)(b * HW + n0 + nn)) * CIN + k0 + c4;
    *(ushort4*)&xth[idx] = oh;
    *(ushort4*)&xtl[idx] = ol;
  }
}

// ---------------------------------------------------------------------------
// Split-bf16 MFMA GEMM v3:  C[b][m][n] = epi( sum_k A[m][k]*B[b][n][k] )
//  - Round-0 staging (everything via global_load_lds, 40x1KB per k-step)
//    but FRAGMENT-MAJOR LDS layout: frag block = [64 lanes][16B], lane l holds
//    row (l&15), k-bytes (l>>4)*16. ds_read_b128 is lane-linear: 0 conflicts.
//    (global_load_lds dest is wave-uniform base + lane*16; per-lane SOURCE
//    address does the fragment gather.)
//  - Minimum-2-phase pipeline (T3): double-buffered LDS, stage(ks+1) issued
//    BEFORE compute(ks); one __syncthreads per k-step (its implicit vmcnt(0)
//    drains stage(ks+1) at the start of iter ks+1). Stage latency hides under
//    ds_read+MFMA of the current step.
//  - LDS = 2*(32KB A + 8KB B) = 80KB exactly -> 2 blocks/CU. Epilogue params
//    read directly from global (broadcast float4, L2-hot) instead of LDS.
// ---------------------------------------------------------------------------
template <int K, int M_TOT, bool BNRELU>
__global__ __launch_bounds__(256, 2) void gemm_mfma(
    const u16* __restrict__ Ah, const u16* __restrict__ Al,
    const u16* __restrict__ Bh, const u16* __restrict__ Bl,
    float* __restrict__ C,
    const float* __restrict__ p0, const float* __restrict__ p1,
    const float* __restrict__ p2, const float* __restrict__ p3,
    const float* __restrict__ p4) {
  constexpr int NSTEP = K / 32;
  // frag-major: [buf][frag][lane][8 u16]; A frags 0..15 hi, 16..31 lo
  __shared__ alignas(16) u16 sA[2][32][512];
  __shared__ alignas(16) u16 sB[2][8][512];

  int t = threadIdx.x, w = t >> 6, l = t & 63;
  int b = blockIdx.z;
  int n0 = blockIdx.x * 64;
  int m0 = blockIdx.y * 256;

  int fr = l & 15, fkc = l >> 4;  // fragment row, k-chunk (of 8 u16)
  const size_t bOff = (size_t)b * HW;

  // stage one 32-k slice (A hi/lo 32 frags + B hi/lo 8 frags); wave w owns
  // frag indices i = w*10 .. w*10+9 (wave-uniform dest base required).
  auto stage = [&](int ks, int buf) {
    int k0 = ks * 32;
#pragma unroll
    for (int c = 0; c < 10; ++c) {
      int i = w * 10 + c;
      const u16* g;
      u16* d;
      if (i < 16) {
        g = Ah + (size_t)(m0 + i * 16 + fr) * K + k0 + fkc * 8;
        d = &sA[buf][i][0];
      } else if (i < 32) {
        g = Al + (size_t)(m0 + (i - 16) * 16 + fr) * K + k0 + fkc * 8;
        d = &sA[buf][i][0];
      } else if (i < 36) {
        g = Bh + (bOff + n0 + (i - 32) * 16 + fr) * (size_t)K + k0 + fkc * 8;
        d = &sB[buf][i - 32][0];
      } else {
        g = Bl + (bOff + n0 + (i - 36) * 16 + fr) * (size_t)K + k0 + fkc * 8;
        d = &sB[buf][i - 32][0];
      }
      async16(d, g);
    }
  };

  f32x4 acc[4][4];
#pragma unroll
  for (int i = 0; i < 4; ++i)
#pragma unroll
    for (int j = 0; j < 4; ++j) acc[i][j] = (f32x4){0.f, 0.f, 0.f, 0.f};

  stage(0, 0);

  for (int ks = 0; ks < NSTEP; ++ks) {
    __syncthreads();  // drains stage(ks); all reads of buf^1 (iter ks-1) done
    if (ks + 1 < NSTEP) stage(ks + 1, (ks + 1) & 1);  // overlap with compute
    int cur = ks & 1;
    bf16x8 ah[4], al[4], bh[4], bl[4];
#pragma unroll
    for (int mt = 0; mt < 4; ++mt) {
      ah[mt] = *(const bf16x8*)&sA[cur][w * 4 + mt][l * 8];
      al[mt] = *(const bf16x8*)&sA[cur][16 + w * 4 + mt][l * 8];
    }
#pragma unroll
    for (int nt = 0; nt < 4; ++nt) {
      bh[nt] = *(const bf16x8*)&sB[cur][nt][l * 8];
      bl[nt] = *(const bf16x8*)&sB[cur][4 + nt][l * 8];
    }
#pragma unroll
    for (int mt = 0; mt < 4; ++mt)
#pragma unroll
      for (int nt = 0; nt < 4; ++nt) {
        acc[mt][nt] = __builtin_amdgcn_mfma_f32_16x16x32_bf16(ah[mt], bh[nt], acc[mt][nt], 0, 0, 0);
        acc[mt][nt] = __builtin_amdgcn_mfma_f32_16x16x32_bf16(ah[mt], bl[nt], acc[mt][nt], 0, 0, 0);
        acc[mt][nt] = __builtin_amdgcn_mfma_f32_16x16x32_bf16(al[mt], bh[nt], acc[mt][nt], 0, 0, 0);
      }
  }

  // epilogue: params via broadcast float4 loads (same addr across fr lanes)
#pragma unroll
  for (int mt = 0; mt < 4; ++mt) {
    int mb = m0 + w * 64 + mt * 16 + (l >> 4) * 4;  // 4 consecutive m rows
    float iv[4], ad[4];
    if (BNRELU) {
      float4 g0 = *(const float4*)&p0[mb];
      float4 g1 = *(const float4*)&p1[mb];
      float4 g2 = *(const float4*)&p2[mb];
      float4 g3 = *(const float4*)&p3[mb];
      float4 g4 = *(const float4*)&p4[mb];
      iv[0] = g1.x * rsqrtf(g4.x + 1e-5f);
      iv[1] = g1.y * rsqrtf(g4.y + 1e-5f);
      iv[2] = g1.z * rsqrtf(g4.z + 1e-5f);
      iv[3] = g1.w * rsqrtf(g4.w + 1e-5f);
      ad[0] = (g0.x - g3.x) * iv[0] + g2.x;
      ad[1] = (g0.y - g3.y) * iv[1] + g2.y;
      ad[2] = (g0.z - g3.z) * iv[2] + g2.z;
      ad[3] = (g0.w - g3.w) * iv[3] + g2.w;
    } else {
      float4 g0 = *(const float4*)&p0[mb];
      ad[0] = g0.x; ad[1] = g0.y; ad[2] = g0.z; ad[3] = g0.w;
    }
#pragma unroll
    for (int nt = 0; nt < 4; ++nt) {
      int n = n0 + nt * 16 + fr;
#pragma unroll
      for (int r = 0; r < 4; ++r) {
        float v = acc[mt][nt][r];
        if (BNRELU)
          v = fmaxf(v * iv[r] + ad[r], 0.f);
        else
          v = v + ad[r];
        C[((size_t)(b * M_TOT) + mb + r) * HW + n] = v;
      }
    }
  }
}

// ---------------------------------------------------------------------------
// valueT[b][cv][128] hi/lo = Wv[cv,:] . xp[b,:,s] + bv[cv]  (s>=110 -> 0)
// ---------------------------------------------------------------------------
__global__ __launch_bounds__(256) void value_kernel(
    const float* __restrict__ Wv, const float* __restrict__ xp,
    const float* __restrict__ bv, u16* __restrict__ vth,
    u16* __restrict__ vtl) {
  int b = blockIdx.x >> 7, s = blockIdx.x & 127;
  int t = threadIdx.x;
  size_t o = ((size_t)(b * 256 + t)) * 128 + s;
  if (s >= S_TOT) { vth[o] = 0; vtl[o] = 0; return; }
  __shared__ float xs[512];
  for (int i = t; i < 512; i += 256) xs[i] = xp[((size_t)b * 512 + i) * S_TOT + s];
  __syncthreads();
  float accv = 0.f;
  const float* wv = Wv + (size_t)t * 512;
  for (int k = 0; k < 512; k += 4) {
    float4 w4 = *(const float4*)&wv[k];
    accv += w4.x * xs[k] + w4.y * xs[k + 1] + w4.z * xs[k + 2] + w4.w * xs[k + 3];
  }
  accv += bv[t];
  u16 h = f2bf(accv);
  vth[o] = h;
  vtl[o] = f2bf(accv - bf2f(h));
}

// ---------------------------------------------------------------------------
// keypT[b][128][256] hi/lo from keyp [b][256][110] fp32 (s>=110 -> 0)
// ---------------------------------------------------------------------------
__global__ __launch_bounds__(256) void convert_key(const float* __restrict__ keyp,
                                                   u16* __restrict__ kth,
                                                   u16* __restrict__ ktl) {
  int b = blockIdx.x;
  int t = threadIdx.x;
  for (int i = t; i < 128 * 256; i += 256) {
    int s = i >> 8, c = i & 255;
    float v = (s < S_TOT) ? keyp[((size_t)(b * 256 + c)) * S_TOT + s] : 0.f;
    u16 h = f2bf(v);
    size_t o = ((size_t)(b * 128 + s)) * 256 + c;
    kth[o] = h;
    ktl[o] = f2bf(v - bf2f(h));
  }
}

// ---------------------------------------------------------------------------
// MFMA attention v2. Per block: 64 pixels, 4 waves. (unchanged)
// ---------------------------------------------------------------------------
__global__ __launch_bounds__(256) void attn_mfma(
    const u16* __restrict__ qh, const u16* __restrict__ ql,
    const u16* __restrict__ kh, const u16* __restrict__ kl,
    const u16* __restrict__ vh, const u16* __restrict__ vl,
    u16* __restrict__ aggh, u16* __restrict__ aggl) {
  __shared__ alignas(16) u16 lds[17408];
  int b = blockIdx.y, pix0 = blockIdx.x * 64;
  int t = threadIdx.x, w = t >> 6, l = t & 63;
  int fr = l & 15, q = l >> 4;

  const u16* kbase_h = kh + (size_t)b * 128 * 256;
  const u16* kbase_l = kl + (size_t)b * 128 * 256;

  f32x4 acc[8];
#pragma unroll
  for (int st = 0; st < 8; ++st) acc[st] = (f32x4){0.f, 0.f, 0.f, 0.f};

  const u16* qbh = qh + ((size_t)(b * HW + pix0 + w * 16 + fr)) * 256 + q * 8;
  const u16* qbl = ql + ((size_t)(b * HW + pix0 + w * 16 + fr)) * 256 + q * 8;

  auto stageK = [&](int ks, int buf) {
    int c0 = ks * 32;
#pragma unroll
    for (int j = 0; j < 4; ++j) {
      int i = t + j * 256;
      int half = i >> 9;
      int idx = i & 511;
      int st = idx >> 6, ll = idx & 63;
      const u16* src = (half ? kbase_l : kbase_h) +
                       (st * 16 + (ll & 15)) * 256 + c0 + (ll >> 4) * 8;
      async16(&lds[buf * 8192 + half * 4096 + idx * 8], src);
    }
  };

  stageK(0, 0);
  for (int ks = 0; ks < 8; ++ks) {
    __syncthreads();
    if (ks < 7) stageK(ks + 1, (ks + 1) & 1);
    bf16x8 ah = *(const bf16x8*)(qbh + ks * 32);
    bf16x8 al = *(const bf16x8*)(qbl + ks * 32);
    const u16* kb = &lds[(ks & 1) * 8192 + l * 8];
#pragma unroll
    for (int st = 0; st < 8; ++st) {
      bf16x8 bh = *(const bf16x8*)(kb + st * 512);
      bf16x8 bl = *(const bf16x8*)(kb + 4096 + st * 512);
      acc[st] = __builtin_amdgcn_mfma_f32_16x16x32_bf16(ah, bh, acc[st], 0, 0, 0);
      acc[st] = __builtin_amdgcn_mfma_f32_16x16x32_bf16(ah, bl, acc[st], 0, 0, 0);
      acc[st] = __builtin_amdgcn_mfma_f32_16x16x32_bf16(al, bh, acc[st], 0, 0, 0);
    }
  }

#pragma unroll
  for (int st = 0; st < 8; ++st)
#pragma unroll
    for (int r = 0; r < 4; ++r) acc[st][r] *= 0.0625f;
  if (fr >= 14) {
#pragma unroll
    for (int r = 0; r < 4; ++r) acc[6][r] = -1e30f;
  }
#pragma unroll
  for (int r = 0; r < 4; ++r) acc[7][r] = -1e30f;

#pragma unroll
  for (int r = 0; r < 4; ++r) {
    float m = -1e30f;
#pragma unroll
    for (int st = 0; st < 8; ++st) m = fmaxf(m, acc[st][r]);
    m = fmaxf(m, __shfl_xor(m, 1));
    m = fmaxf(m, __shfl_xor(m, 2));
    m = fmaxf(m, __shfl_xor(m, 4));
    m = fmaxf(m, __shfl_xor(m, 8));
    float s = 0.f;
#pragma unroll
    for (int st = 0; st < 8; ++st) {
      float e = __expf(acc[st][r] - m);
      acc[st][r] = e;
      s += e;
    }
    s += __shfl_xor(s, 1);
    s += __shfl_xor(s, 2);
    s += __shfl_xor(s, 4);
    s += __shfl_xor(s, 8);
    float inv = 1.f / s;
#pragma unroll
    for (int st = 0; st < 8; ++st) acc[st][r] *= inv;
  }

  __syncthreads();

  int prow = w * 16 + q * 4;
#pragma unroll
  for (int st = 0; st < 8; ++st) {
    int s = st * 16 + fr;
#pragma unroll
    for (int r = 0; r < 4; ++r) {
      float v = acc[st][r];
      u16 h = f2bf(v);
      lds[(prow + r) * 136 + s] = h;
      lds[8704 + (prow + r) * 136 + s] = f2bf(v - bf2f(h));
    }
  }
  __syncthreads();

  f32x4 oacc[4][4];
#pragma unroll
  for (int nt = 0; nt < 4; ++nt)
#pragma unroll
    for (int pt = 0; pt < 4; ++pt) oacc[nt][pt] = (f32x4){0.f, 0.f, 0.f, 0.f};

  const u16* vbh = vh + ((size_t)(b * 256 + w * 64 + fr)) * 128 + q * 8;
  const u16* vbl = vl + ((size_t)(b * 256 + w * 64 + fr)) * 128 + q * 8;

#pragma unroll
  for (int kc = 0; kc < 4; ++kc) {
    bf16x8 ph[4], pl[4];
#pragma unroll
    for (int pt = 0; pt < 4; ++pt) {
      ph[pt] = *(const bf16x8*)&lds[(pt * 16 + fr) * 136 + kc * 32 + q * 8];
      pl[pt] = *(const bf16x8*)&lds[8704 + (pt * 16 + fr) * 136 + kc * 32 + q * 8];
    }
#pragma unroll
    for (int nt = 0; nt < 4; ++nt) {
      bf16x8 a_h = *(const bf16x8*)(vbh + (size_t)nt * 16 * 128 + kc * 32);
      bf16x8 a_l = *(const bf16x8*)(vbl + (size_t)nt * 16 * 128 + kc * 32);
#pragma unroll
      for (int pt = 0; pt < 4; ++pt) {
        oacc[nt][pt] = __builtin_amdgcn_mfma_f32_16x16x32_bf16(a_h, ph[pt], oacc[nt][pt], 0, 0, 0);
        oacc[nt][pt] = __builtin_amdgcn_mfma_f32_16x16x32_bf16(a_h, pl[pt], oacc[nt][pt], 0, 0, 0);
        oacc[nt][pt] = __builtin_amdgcn_mfma_f32_16x16x32_bf16(a_l, ph[pt], oacc[nt][pt], 0, 0, 0);
      }
    }
  }

#pragma unroll
  for (int nt = 0; nt < 4; ++nt) {
#pragma unroll
    for (int pt = 0; pt < 4; ++pt) {
      ushort4 oh, ol;
      float v0 = oacc[nt][pt][0], v1 = oacc[nt][pt][1];
      float v2 = oacc[nt][pt][2], v3 = oacc[nt][pt][3];
      oh.x = f2bf(v0); ol.x = f2bf(v0 - bf2f(oh.x));
      oh.y = f2bf(v1); ol.y = f2bf(v1 - bf2f(oh.y));
      oh.z = f2bf(v2); ol.z = f2bf(v2 - bf2f(oh.z));
      oh.w = f2bf(v3); ol.w = f2bf(v3 - bf2f(oh.w));
      size_t o = ((size_t)(b * HW + pix0 + pt * 16 + fr)) * 256 + (w * 4 + nt) * 16 + q * 4;
      *(ushort4*)&aggh[o] = oh;
      *(ushort4*)&aggl[o] = ol;
    }
  }
}

extern "C" void kernel_launch(void* const* d_in, const int* in_sizes, int n_in,
                              void* d_out, int out_size, void* d_ws, size_t ws_size,
                              hipStream_t stream) {
  (void)in_sizes; (void)n_in; (void)out_size; (void)ws_size;
  const float* x     = (const float*)d_in[0];
  const float* Wk    = (const float*)d_in[1];
  const float* bk    = (const float*)d_in[2];
  const float* gamma = (const float*)d_in[3];
  const float* beta  = (const float*)d_in[4];
  const float* mean  = (const float*)d_in[5];
  const float* var   = (const float*)d_in[6];
  const float* Wv    = (const float*)d_in[7];
  const float* bv    = (const float*)d_in[8];
  const float* Wo    = (const float*)d_in[9];
  const float* bo    = (const float*)d_in[10];
  float* out = (float*)d_out;

  char* p = (char*)d_ws;
  float* kq = (float*)p;      p += (size_t)14745600 * 4;   // 4*256*14400 fp32
  u16* xth = (u16*)p;         p += (size_t)29491200 * 2;   // 4*14400*512 bf16
  u16* xtl = (u16*)p;         p += (size_t)29491200 * 2;
  u16* wkh = (u16*)p;         p += 131072 * 2;
  u16* wkl = (u16*)p;         p += 131072 * 2;
  u16* woh = (u16*)p;         p += 131072 * 2;
  u16* wol = (u16*)p;         p += 131072 * 2;
  float* xp = (float*)p;      p += (size_t)4 * 512 * 110 * 4;
  float* keyp = (float*)p;    p += (size_t)4 * 256 * 110 * 4;
  u16* vth = (u16*)p;         p += (size_t)4 * 256 * 128 * 2;
  u16* vtl = (u16*)p;         p += (size_t)4 * 256 * 128 * 2;
  u16* kth = (u16*)p;         p += (size_t)4 * 128 * 256 * 2;
  u16* ktl = (u16*)p;         p += (size_t)4 * 128 * 256 * 2;
  // aliases: xth/xtl (59MB each) are dead after gemm_kq.
  // first half -> agg hi/lo, second half -> kqT hi/lo
  u16* aggh = xth;
  u16* kqth = xth + (size_t)14745600;
  u16* aggl = xtl;
  u16* kqtl = xtl + (size_t)14745600;

  // weight splits
  convert_w<<<512, 256, 0, stream>>>(Wk, wkh, wkl, 256 * 512);
  convert_w<<<512, 256, 0, stream>>>(Wo, woh, wol, 512 * 256);
  // X -> transposed bf16 hi/lo
  convert_t<512><<<dim3(225, 8, 4), 256, 0, stream>>>(x, xth, xtl);
  // pyramid-pool x (pooling commutes with 1x1 conv for value)
  pool_kernel<<<dim3(4 * 512), dim3(256), 0, stream>>>(x, xp);
  // valueT = split(conv_v(pooled x) + bv), s-padded
  value_kernel<<<dim3(4 * 128), dim3(256), 0, stream>>>(Wv, xp, bv, vth, vtl);
  // kq = relu(BN(conv_k(x)))  [split-bf16 MFMA, 2-phase pipelined]
  gemm_mfma<512, 256, true><<<dim3(225, 1, 4), 256, 0, stream>>>(
      wkh, wkl, xth, xtl, kq, bk, gamma, beta, mean, var);
  // kqT (query in A-fragment layout)
  convert_t<256><<<dim3(225, 4, 4), 256, 0, stream>>>(kq, kqth, kqtl);
  // key = ppm(kq) -> keypT split, s-padded
  pool_kernel<<<dim3(4 * 256), dim3(256), 0, stream>>>(kq, keyp);
  convert_key<<<dim3(4), dim3(256), 0, stream>>>(keyp, kth, ktl);
  // fused MFMA attention -> agg split bf16
  attn_mfma<<<dim3(225, 4), 256, 0, stream>>>(kqth, kqtl, kth, ktl, vth, vtl,
                                              aggh, aggl);
  // out = conv_out(agg) + bo  [split-bf16 MFMA, 2-phase pipelined]
  gemm_mfma<256, 512, false><<<dim3(225, 2, 4), 256, 0, stream>>>(
      woh, wol, aggh, aggl, out, bo, nullptr, nullptr, nullptr, nullptr);
}